// Round 2
// baseline (637.867 us; speedup 1.0000x reference)
//
#include <hip/hip_runtime.h>

typedef _Float16 f16;
typedef _Float16 f16x8 __attribute__((ext_vector_type(8)));
typedef float f32x4 __attribute__((ext_vector_type(4)));

static __device__ __forceinline__ f32x4 mfma16(f16x8 a, f16x8 b, f32x4 c) {
  return __builtin_amdgcn_mfma_f32_16x16x32_f16(a, b, c, 0, 0, 0);
}

// ---------------- pack kernels ----------------
__global__ void pack_f16_kernel(const float* __restrict__ s, f16* __restrict__ d, int n) {
  int i = blockIdx.x * 256 + threadIdx.x;
  if (i < n) d[i] = (f16)s[i];
}

// relK padded: row 2047 -> 0
__global__ void pack_relk_kernel(const float* __restrict__ relk, f16* __restrict__ dst) {
  int idx = blockIdx.x * 256 + threadIdx.x;  // 2048*64
  dst[idx] = (idx < 2047 * 64) ? (f16)relk[idx] : (f16)0.f;
}

// relVT[d][p] = relative_v[p][d], padded col p==2047 -> 0
__global__ void pack_relvt_kernel(const float* __restrict__ relv, f16* __restrict__ dst) {
  int idx = blockIdx.x * 256 + threadIdx.x;  // 64*2048 threads
  int dd = idx >> 11, p = idx & 2047;
  dst[idx] = (p < 2047) ? (f16)relv[p * 64 + dd] : (f16)0.f;
}

// ---------------- generic B^T GEMM: C[i,j] = (sum_k A[i,k]*B[j,k] + bias)*oscale ----
template <int OUT_F32, int BIAS_ROW>
__global__ __launch_bounds__(256, 2) void gemm_bt(
    const f16* __restrict__ A, const f16* __restrict__ B,
    const float* __restrict__ bias, void* __restrict__ Cout,
    int M, int N, int Kd, float oscale) {
  __shared__ __align__(16) f16 Al[128 * 72];
  __shared__ __align__(16) f16 Bl[128 * 72];
  const int tid = threadIdx.x;
  const int w = tid >> 6, lane = tid & 63;
  const int l15 = lane & 15, hi = lane >> 4;
  const long i0 = (long)blockIdx.y * 128, j0 = (long)blockIdx.x * 128;
  const int wr = (w >> 1) * 64, wc = (w & 1) * 64;

  f32x4 acc[4][4];
#pragma unroll
  for (int a = 0; a < 4; a++)
#pragma unroll
    for (int b2 = 0; b2 < 4; b2++) acc[a][b2] = (f32x4){0.f, 0.f, 0.f, 0.f};

  for (int k0 = 0; k0 < Kd; k0 += 64) {
    __syncthreads();
#pragma unroll
    for (int s = 0; s < 4; s++) {
      int tau = tid + 256 * s;
      int r = tau >> 3, c = (tau & 7) * 8;
      *(uint4*)&Al[r * 72 + c] = *(const uint4*)(A + (i0 + r) * Kd + k0 + c);
      *(uint4*)&Bl[r * 72 + c] = *(const uint4*)(B + (j0 + r) * Kd + k0 + c);
    }
    __syncthreads();
#pragma unroll
    for (int ks = 0; ks < 2; ks++) {
      f16x8 af[4], bf[4];
#pragma unroll
      for (int mb = 0; mb < 4; mb++)
        af[mb] = *(const f16x8*)&Al[(wr + mb * 16 + l15) * 72 + ks * 32 + hi * 8];
#pragma unroll
      for (int nb = 0; nb < 4; nb++)
        bf[nb] = *(const f16x8*)&Bl[(wc + nb * 16 + l15) * 72 + ks * 32 + hi * 8];
#pragma unroll
      for (int mb = 0; mb < 4; mb++)
#pragma unroll
        for (int nb = 0; nb < 4; nb++) acc[mb][nb] = mfma16(af[mb], bf[nb], acc[mb][nb]);
    }
  }
#pragma unroll
  for (int mb = 0; mb < 4; mb++) {
#pragma unroll
    for (int nb = 0; nb < 4; nb++) {
      long row = i0 + wr + mb * 16 + hi * 4;
      long col = j0 + wc + nb * 16 + l15;
      float bc = BIAS_ROW ? 0.f : bias[col];
#pragma unroll
      for (int i = 0; i < 4; i++) {
        float v = acc[mb][nb][i] + (BIAS_ROW ? bias[row + i] : bc);
        v *= oscale;
        if (OUT_F32)
          ((float*)Cout)[(row + i) * N + col] = v;
        else
          ((f16*)Cout)[(row + i) * N + col] = (f16)v;
      }
    }
  }
}

// ---------------- fused relative-position flash attention ----------------
// 1D grid 2048 = 16 qtiles x 128 b*h, XCD-swizzled. 4 waves, BM=BN=64.
// Pipelined: all global tiles prefetched one iteration ahead into registers.
// Only 2 barriers per K-tile: staged-tile buffers are the only cross-wave LDS.
// QR/Pskew (aliased) and Pmain are intra-wave (each wave owns its 16 q-rows).
__global__ __launch_bounds__(256, 2) void attn_kernel(
    const f16* __restrict__ Qh, const f16* __restrict__ Kh,
    const f16* __restrict__ Vth, const f16* __restrict__ relKh,
    const f16* __restrict__ relVTh, f16* __restrict__ AO) {
  __shared__ __align__(16) f16 ldsK[64 * 72];    // K tile
  __shared__ __align__(16) f16 ldsRK[128 * 72];  // relK band
  __shared__ __align__(16) f16 ldsQR[64 * 136];  // QR, then Pskew (intra-wave)
  __shared__ __align__(16) f16 ldsP[64 * 72];    // Pmain (intra-wave)
  __shared__ __align__(16) f16 ldsRV[64 * 136];  // relVT band
  __shared__ __align__(16) f16 ldsV[64 * 72];    // V^T tile
  // total = 80896 B <= 80KB -> 2 blocks/CU

  const int tid = threadIdx.x;
  const int w = tid >> 6, lane = tid & 63;
  const int l15 = lane & 15, hi = lane >> 4;
  // XCD swizzle: 16 q-tiles of one (b,h) land on one XCD, temporally adjacent
  const int flat = blockIdx.x;
  const int xcd = flat & 7, slot = flat >> 3;
  const int bh = xcd * 16 + (slot >> 4);
  const int qt = slot & 15;
  const int b = bh >> 4, h = bh & 15;
  const int l0 = qt * 64;

  // Q fragments (row = l0 + 16w + l15), k-halves ks=0,1
  const long qoff = ((long)(b * 1024 + l0 + w * 16 + l15)) * 1024 + h * 64 + hi * 8;
  const f16x8 qf0 = *(const f16x8*)(Qh + qoff);
  const f16x8 qf1 = *(const f16x8*)(Qh + qoff + 32);

  f32x4 acc_o[4];
#pragma unroll
  for (int cf = 0; cf < 4; cf++) acc_o[cf] = (f32x4){0.f, 0.f, 0.f, 0.f};
  float mrow[4] = {-1e30f, -1e30f, -1e30f, -1e30f};
  float lsum[4] = {0.f, 0.f, 0.f, 0.f};

  uint4 kreg[2], rkreg[4], vreg[2], rvreg[4];
  auto issue_loads = [&](int ktn) {
    const int r0n = ktn * 64;
    const int basen = 960 + r0n - l0;  // band start (multiple of 64, >=0, <=1920)
#pragma unroll
    for (int s = 0; s < 2; s++) {
      int tau = tid + 256 * s;
      int r = tau >> 3, c = (tau & 7) * 8;
      kreg[s] = *(const uint4*)(Kh + ((long)(b * 1024 + r0n + r)) * 1024 + h * 64 + c);
    }
#pragma unroll
    for (int s = 0; s < 4; s++) {
      int tau = tid + 256 * s;
      int r = tau >> 3, c = (tau & 7) * 8;
      rkreg[s] = *(const uint4*)(relKh + (basen + r) * 64 + c);
    }
#pragma unroll
    for (int s = 0; s < 2; s++) {
      int tau = tid + 256 * s;
      int d = tau >> 3, c = (tau & 7) * 8;
      vreg[s] = *(const uint4*)(Vth + ((long)(h * 64 + d)) * 8192 + b * 1024 + r0n + c);
    }
#pragma unroll
    for (int s = 0; s < 4; s++) {
      int tau = tid + 256 * s;
      int d = tau >> 4, c = (tau & 15) * 8;
      rvreg[s] = *(const uint4*)(relVTh + d * 2048 + basen + c);
    }
  };

  issue_loads(0);

  for (int kt = 0; kt < 16; kt++) {
    __syncthreads();  // B0: all waves done reading staged buffers (prev iter)
    // stage prefetched regs -> LDS (lgkm only; vmcnt drained by barrier logic)
#pragma unroll
    for (int s = 0; s < 2; s++) {
      int tau = tid + 256 * s;
      int r = tau >> 3, c = (tau & 7) * 8;
      *(uint4*)&ldsK[r * 72 + c] = kreg[s];
    }
#pragma unroll
    for (int s = 0; s < 4; s++) {
      int tau = tid + 256 * s;
      int r = tau >> 3, c = (tau & 7) * 8;
      *(uint4*)&ldsRK[r * 72 + c] = rkreg[s];
    }
#pragma unroll
    for (int s = 0; s < 2; s++) {
      int tau = tid + 256 * s;
      int d = tau >> 3, c = (tau & 7) * 8;
      *(uint4*)&ldsV[d * 72 + c] = vreg[s];
    }
#pragma unroll
    for (int s = 0; s < 4; s++) {
      int tau = tid + 256 * s;
      int d = tau >> 4, c = (tau & 15) * 8;
      *(uint4*)&ldsRV[d * 136 + c] = rvreg[s];
    }
    __syncthreads();  // B1: staged tiles visible to all waves

    // issue next iteration's global loads; latency hides under this iter's compute
    if (kt < 15) issue_loads(kt + 1);

    // S = Q*(K/8)^T ; QR[l,c] = Q[l,:].relK[base+c,:]
    f32x4 sacc[4], qracc[8];
#pragma unroll
    for (int cf = 0; cf < 4; cf++) sacc[cf] = (f32x4){0.f, 0.f, 0.f, 0.f};
#pragma unroll
    for (int cf = 0; cf < 8; cf++) qracc[cf] = (f32x4){0.f, 0.f, 0.f, 0.f};
#pragma unroll
    for (int ks = 0; ks < 2; ks++) {
      f16x8 qf = ks ? qf1 : qf0;
#pragma unroll
      for (int cf = 0; cf < 4; cf++) {
        f16x8 kf = *(const f16x8*)&ldsK[(cf * 16 + l15) * 72 + ks * 32 + hi * 8];
        sacc[cf] = mfma16(qf, kf, sacc[cf]);
      }
#pragma unroll
      for (int cf = 0; cf < 8; cf++) {
        f16x8 rf = *(const f16x8*)&ldsRK[(cf * 16 + l15) * 72 + ks * 32 + hi * 8];
        qracc[cf] = mfma16(qf, rf, qracc[cf]);
      }
    }
    // write QR (own 16 rows only -> intra-wave, no barrier)
#pragma unroll
    for (int cf = 0; cf < 8; cf++)
#pragma unroll
      for (int i = 0; i < 4; i++)
        ldsQR[(w * 16 + hi * 4 + i) * 136 + cf * 16 + l15] = (f16)qracc[cf][i];
    asm volatile("s_waitcnt lgkmcnt(0)" ::: "memory");  // QR visible to own wave

    // gather rel scores (diagonal, own rows) + online softmax
    float sv[4][4];
#pragma unroll
    for (int cf = 0; cf < 4; cf++)
#pragma unroll
      for (int i = 0; i < 4; i++) {
        int li = w * 16 + hi * 4 + i;
        int ri = cf * 16 + l15;
        sv[cf][i] = sacc[cf][i] + (float)ldsQR[li * 136 + 63 + ri - li];
      }
    float rmax[4];
#pragma unroll
    for (int i = 0; i < 4; i++)
      rmax[i] = fmaxf(fmaxf(sv[0][i], sv[1][i]), fmaxf(sv[2][i], sv[3][i]));
#pragma unroll
    for (int m = 1; m < 16; m <<= 1)
#pragma unroll
      for (int i = 0; i < 4; i++) rmax[i] = fmaxf(rmax[i], __shfl_xor(rmax[i], m, 64));
    float pw[4][4], rsum[4];
#pragma unroll
    for (int i = 0; i < 4; i++) {
      float mn = fmaxf(mrow[i], rmax[i]);
      float al = __expf(mrow[i] - mn);
      mrow[i] = mn;
      lsum[i] *= al;
#pragma unroll
      for (int cf = 0; cf < 4; cf++) acc_o[cf][i] *= al;
      rsum[i] = 0.f;
    }
#pragma unroll
    for (int cf = 0; cf < 4; cf++)
#pragma unroll
      for (int i = 0; i < 4; i++) {
        float p = __expf(sv[cf][i] - mrow[i]);
        pw[cf][i] = p;
        rsum[i] += p;
      }
#pragma unroll
    for (int m = 1; m < 16; m <<= 1)
#pragma unroll
      for (int i = 0; i < 4; i++) rsum[i] += __shfl_xor(rsum[i], m, 64);
#pragma unroll
    for (int i = 0; i < 4; i++) lsum[i] += rsum[i];

    // all gather reads retired (sv consumed); safe to overwrite QR with Pskew
    asm volatile("s_waitcnt lgkmcnt(0)" ::: "memory");
    // zero own Pskew rows (cols 0..127), then scatter P into Pmain+Pskew
    const uint4 z4 = make_uint4(0u, 0u, 0u, 0u);
#pragma unroll
    for (int s = 0; s < 4; s++) {
      int tau = lane + 64 * s;  // 16 rows * 16 chunks
      int rr = w * 16 + (tau >> 4), cc = (tau & 15) * 8;
      *(uint4*)&ldsQR[rr * 136 + cc] = z4;
    }
#pragma unroll
    for (int cf = 0; cf < 4; cf++)
#pragma unroll
      for (int i = 0; i < 4; i++) {
        int li = w * 16 + hi * 4 + i;
        int ri = cf * 16 + l15;
        f16 ph = (f16)pw[cf][i];
        ldsP[li * 72 + ri] = ph;
        ldsQR[li * 136 + 63 + ri - li] = ph;  // skew: col = 63 + r - l
      }
    asm volatile("s_waitcnt lgkmcnt(0)" ::: "memory");  // P visible to own wave

    // O += P @ V  (B-frag rows = d from V^T tile)
#pragma unroll
    for (int ks = 0; ks < 2; ks++) {
      f16x8 pa = *(const f16x8*)&ldsP[(w * 16 + l15) * 72 + ks * 32 + hi * 8];
#pragma unroll
      for (int cf = 0; cf < 4; cf++) {
        f16x8 vb = *(const f16x8*)&ldsV[(cf * 16 + l15) * 72 + ks * 32 + hi * 8];
        acc_o[cf] = mfma16(pa, vb, acc_o[cf]);
      }
    }
    // O += Pskew @ relV_band  (K-dim = 128)
#pragma unroll
    for (int ks = 0; ks < 4; ks++) {
      f16x8 pa = *(const f16x8*)&ldsQR[(w * 16 + l15) * 136 + ks * 32 + hi * 8];
#pragma unroll
      for (int cf = 0; cf < 4; cf++) {
        f16x8 rb = *(const f16x8*)&ldsRV[(cf * 16 + l15) * 136 + ks * 32 + hi * 8];
        acc_o[cf] = mfma16(pa, rb, acc_o[cf]);
      }
    }
  }
  // epilogue: normalize, store fp16 to AO[b*1024+l][h*64+d]
#pragma unroll
  for (int cf = 0; cf < 4; cf++)
#pragma unroll
    for (int i = 0; i < 4; i++) {
      float v = acc_o[cf][i] / lsum[i];
      AO[((long)(b * 1024 + l0 + w * 16 + hi * 4 + i)) * 1024 + h * 64 + cf * 16 + l15] =
          (f16)v;
    }
}

// ---------------- launch ----------------
extern "C" void kernel_launch(void* const* d_in, const int* in_sizes, int n_in,
                              void* d_out, int out_size, void* d_ws, size_t ws_size,
                              hipStream_t stream) {
  const float* x = (const float*)d_in[0];
  const float* Wq = (const float*)d_in[1];
  const float* bq = (const float*)d_in[2];
  const float* Wk = (const float*)d_in[3];
  const float* bk = (const float*)d_in[4];
  const float* Wv = (const float*)d_in[5];
  const float* bv = (const float*)d_in[6];
  const float* Wo = (const float*)d_in[7];
  const float* bo = (const float*)d_in[8];
  const float* relk = (const float*)d_in[9];
  const float* relv = (const float*)d_in[10];
  float* out = (float*)d_out;

  char* ws = (char*)d_ws;
  size_t off = 0;
  auto alloc = [&](size_t bytes) {
    char* p = ws + off;
    off += (bytes + 255) & ~(size_t)255;
    return p;
  };
  f16* xh = (f16*)alloc(8192ull * 1024 * 2);
  f16* Wqh = (f16*)alloc(1024ull * 1024 * 2);
  f16* Wkh = (f16*)alloc(1024ull * 1024 * 2);
  f16* Wvh = (f16*)alloc(1024ull * 1024 * 2);
  f16* Woh = (f16*)alloc(1024ull * 1024 * 2);
  f16* relKh = (f16*)alloc(2048ull * 64 * 2);
  f16* relVTh = (f16*)alloc(64ull * 2048 * 2);
  f16* Qh = (f16*)alloc(8192ull * 1024 * 2);
  f16* Kh = (f16*)alloc(8192ull * 1024 * 2);
  f16* Vth = (f16*)alloc(1024ull * 8192 * 2);
  f16* AOh = (f16*)alloc(8192ull * 1024 * 2);
  if (ws_size < off) return;  // workspace too small: fail loudly at validation

  pack_f16_kernel<<<32768, 256, 0, stream>>>(x, xh, 8192 * 1024);
  pack_f16_kernel<<<4096, 256, 0, stream>>>(Wq, Wqh, 1024 * 1024);
  pack_f16_kernel<<<4096, 256, 0, stream>>>(Wk, Wkh, 1024 * 1024);
  pack_f16_kernel<<<4096, 256, 0, stream>>>(Wv, Wvh, 1024 * 1024);
  pack_f16_kernel<<<4096, 256, 0, stream>>>(Wo, Woh, 1024 * 1024);
  pack_relk_kernel<<<512, 256, 0, stream>>>(relk, relKh);
  pack_relvt_kernel<<<512, 256, 0, stream>>>(relv, relVTh);

  dim3 g1(8, 64);  // N/128, M/128
  gemm_bt<0, 0><<<g1, 256, 0, stream>>>(xh, Wqh, bq, Qh, 8192, 1024, 1024, 1.0f);
  gemm_bt<0, 0><<<g1, 256, 0, stream>>>(xh, Wkh, bk, Kh, 8192, 1024, 1024, 0.125f);
  dim3 g2(64, 8);  // V^T = Wv @ x^T : M=1024, N=8192
  gemm_bt<0, 1><<<g2, 256, 0, stream>>>(Wvh, xh, bv, Vth, 1024, 8192, 1024, 1.0f);

  attn_kernel<<<2048, 256, 0, stream>>>(Qh, Kh, Vth, relKh, relVTh, AOh);

  gemm_bt<1, 0><<<g1, 256, 0, stream>>>(AOh, Woh, bo, out, 8192, 1024, 1024, 1.0f);
}

// Round 3
// 423.681 us; speedup vs baseline: 1.5055x; 1.5055x over previous
//
#include <hip/hip_runtime.h>

typedef _Float16 f16;
typedef _Float16 f16x8 __attribute__((ext_vector_type(8)));
typedef float f32x4 __attribute__((ext_vector_type(4)));

static __device__ __forceinline__ f32x4 mfma16(f16x8 a, f16x8 b, f32x4 c) {
  return __builtin_amdgcn_mfma_f32_16x16x32_f16(a, b, c, 0, 0, 0);
}

// ---------------- pack kernels ----------------
__global__ void pack_f16_kernel(const float* __restrict__ s, f16* __restrict__ d, int n) {
  int i = blockIdx.x * 256 + threadIdx.x;
  if (i < n) d[i] = (f16)s[i];
}

// relK padded: row 2047 -> 0
__global__ void pack_relk_kernel(const float* __restrict__ relk, f16* __restrict__ dst) {
  int idx = blockIdx.x * 256 + threadIdx.x;  // 2048*64
  dst[idx] = (idx < 2047 * 64) ? (f16)relk[idx] : (f16)0.f;
}

// relVT[d][p] = relative_v[p][d], padded col p==2047 -> 0
__global__ void pack_relvt_kernel(const float* __restrict__ relv, f16* __restrict__ dst) {
  int idx = blockIdx.x * 256 + threadIdx.x;  // 64*2048 threads
  int dd = idx >> 11, p = idx & 2047;
  dst[idx] = (p < 2047) ? (f16)relv[p * 64 + dd] : (f16)0.f;
}

// ---------------- generic B^T GEMM: C[i,j] = (sum_k A[i,k]*B[j,k] + bias)*oscale ----
template <int OUT_F32, int BIAS_ROW>
__global__ __launch_bounds__(256, 2) void gemm_bt(
    const f16* __restrict__ A, const f16* __restrict__ B,
    const float* __restrict__ bias, void* __restrict__ Cout,
    int M, int N, int Kd, float oscale) {
  __shared__ __align__(16) f16 Al[128 * 72];
  __shared__ __align__(16) f16 Bl[128 * 72];
  const int tid = threadIdx.x;
  const int w = tid >> 6, lane = tid & 63;
  const int l15 = lane & 15, hi = lane >> 4;
  const long i0 = (long)blockIdx.y * 128, j0 = (long)blockIdx.x * 128;
  const int wr = (w >> 1) * 64, wc = (w & 1) * 64;

  f32x4 acc[4][4];
#pragma unroll
  for (int a = 0; a < 4; a++)
#pragma unroll
    for (int b2 = 0; b2 < 4; b2++) acc[a][b2] = (f32x4){0.f, 0.f, 0.f, 0.f};

  for (int k0 = 0; k0 < Kd; k0 += 64) {
    __syncthreads();
#pragma unroll
    for (int s = 0; s < 4; s++) {
      int tau = tid + 256 * s;
      int r = tau >> 3, c = (tau & 7) * 8;
      *(uint4*)&Al[r * 72 + c] = *(const uint4*)(A + (i0 + r) * Kd + k0 + c);
      *(uint4*)&Bl[r * 72 + c] = *(const uint4*)(B + (j0 + r) * Kd + k0 + c);
    }
    __syncthreads();
#pragma unroll
    for (int ks = 0; ks < 2; ks++) {
      f16x8 af[4], bf[4];
#pragma unroll
      for (int mb = 0; mb < 4; mb++)
        af[mb] = *(const f16x8*)&Al[(wr + mb * 16 + l15) * 72 + ks * 32 + hi * 8];
#pragma unroll
      for (int nb = 0; nb < 4; nb++)
        bf[nb] = *(const f16x8*)&Bl[(wc + nb * 16 + l15) * 72 + ks * 32 + hi * 8];
#pragma unroll
      for (int mb = 0; mb < 4; mb++)
#pragma unroll
        for (int nb = 0; nb < 4; nb++) acc[mb][nb] = mfma16(af[mb], bf[nb], acc[mb][nb]);
    }
  }
#pragma unroll
  for (int mb = 0; mb < 4; mb++) {
#pragma unroll
    for (int nb = 0; nb < 4; nb++) {
      long row = i0 + wr + mb * 16 + hi * 4;
      long col = j0 + wc + nb * 16 + l15;
      float bc = BIAS_ROW ? 0.f : bias[col];
#pragma unroll
      for (int i = 0; i < 4; i++) {
        float v = acc[mb][nb][i] + (BIAS_ROW ? bias[row + i] : bc);
        v *= oscale;
        if (OUT_F32)
          ((float*)Cout)[(row + i) * N + col] = v;
        else
          ((f16*)Cout)[(row + i) * N + col] = (f16)v;
      }
    }
  }
}

// ---------------- fused relative-position flash attention ----------------
// 1D grid 2048 = 16 qtiles x 128 b*h, XCD-swizzled. 4 waves, BM=BN=64.
// Pipelined: next tile prefetched into NAMED registers (no arrays/lambda ->
// no scratch spill), staged to LDS at the next iteration's head.
// 2 barriers per K-tile; QR/Pskew (aliased) and Pmain are intra-wave.
#define PREFETCH(R0N)                                    \
  do {                                                   \
    pk0 = *(const uint4*)(kpA + (long)(R0N) * 1024);     \
    pk1 = *(const uint4*)(kpB + (long)(R0N) * 1024);     \
    prk0 = *(const uint4*)(rkpA + (R0N) * 64);           \
    prk1 = *(const uint4*)(rkpB + (R0N) * 64);           \
    prk2 = *(const uint4*)(rkpC + (R0N) * 64);           \
    prk3 = *(const uint4*)(rkpD + (R0N) * 64);           \
    pv0 = *(const uint4*)(vpA + (R0N));                  \
    pv1 = *(const uint4*)(vpB + (R0N));                  \
    prv0 = *(const uint4*)(rvpA + (R0N));                \
    prv1 = *(const uint4*)(rvpB + (R0N));                \
    prv2 = *(const uint4*)(rvpC + (R0N));                \
    prv3 = *(const uint4*)(rvpD + (R0N));                \
  } while (0)

__global__ __launch_bounds__(256, 2) void attn_kernel(
    const f16* __restrict__ Qh, const f16* __restrict__ Kh,
    const f16* __restrict__ Vth, const f16* __restrict__ relKh,
    const f16* __restrict__ relVTh, f16* __restrict__ AO) {
  __shared__ __align__(16) f16 ldsK[64 * 72];    // K tile
  __shared__ __align__(16) f16 ldsRK[128 * 72];  // relK band
  __shared__ __align__(16) f16 ldsQR[64 * 136];  // QR, then Pskew (intra-wave)
  __shared__ __align__(16) f16 ldsP[64 * 72];    // Pmain (intra-wave)
  __shared__ __align__(16) f16 ldsRV[64 * 136];  // relVT band
  __shared__ __align__(16) f16 ldsV[64 * 72];    // V^T tile
  // total = 80896 B -> 2 blocks/CU (LDS-limited)

  const int tid = threadIdx.x;
  const int w = tid >> 6, lane = tid & 63;
  const int l15 = lane & 15, hi = lane >> 4;
  // XCD swizzle: 16 q-tiles of one (b,h) land on one XCD, temporally adjacent
  const int flat = blockIdx.x;
  const int xcd = flat & 7, slot = flat >> 3;
  const int bh = xcd * 16 + (slot >> 4);
  const int qt = slot & 15;
  const int b = bh >> 4, h = bh & 15;
  const int l0 = qt * 64;

  // per-thread staging geometry
  const int t3 = tid >> 3, c8 = (tid & 7) * 8;
  const int t4 = tid >> 4, c16 = (tid & 15) * 8;
  // global base pointers (element offsets added per-iteration are tiny)
  const f16* kpA = Kh + ((long)(b * 1024 + t3)) * 1024 + h * 64 + c8;
  const f16* kpB = kpA + 32l * 1024;
  const f16* rkpA = relKh + (long)(960 - l0 + t3) * 64 + c8;
  const f16* rkpB = rkpA + 32l * 64;
  const f16* rkpC = rkpA + 64l * 64;
  const f16* rkpD = rkpA + 96l * 64;
  const f16* vpA = Vth + ((long)(h * 64 + t3)) * 8192 + b * 1024 + c8;
  const f16* vpB = vpA + 32l * 8192;
  const f16* rvpA = relVTh + (long)t4 * 2048 + (960 - l0) + c16;
  const f16* rvpB = rvpA + 16l * 2048;
  const f16* rvpC = rvpA + 32l * 2048;
  const f16* rvpD = rvpA + 48l * 2048;
  // LDS write offsets
  const int oKA = t3 * 72 + c8, oKB = (t3 + 32) * 72 + c8;
  const int oRKA = oKA, oRKB = oKB, oRKC = (t3 + 64) * 72 + c8, oRKD = (t3 + 96) * 72 + c8;
  const int oRVA = t4 * 136 + c16, oRVB = (t4 + 16) * 136 + c16,
            oRVC = (t4 + 32) * 136 + c16, oRVD = (t4 + 48) * 136 + c16;

  // Q fragments (row = l0 + 16w + l15), k-halves ks=0,1
  const long qoff = ((long)(b * 1024 + l0 + w * 16 + l15)) * 1024 + h * 64 + hi * 8;
  const f16x8 qf0 = *(const f16x8*)(Qh + qoff);
  const f16x8 qf1 = *(const f16x8*)(Qh + qoff + 32);

  f32x4 acc_o[4];
#pragma unroll
  for (int cf = 0; cf < 4; cf++) acc_o[cf] = (f32x4){0.f, 0.f, 0.f, 0.f};
  float mrow[4] = {-1e30f, -1e30f, -1e30f, -1e30f};
  float lsum[4] = {0.f, 0.f, 0.f, 0.f};

  uint4 pk0, pk1, prk0, prk1, prk2, prk3, pv0, pv1, prv0, prv1, prv2, prv3;
  PREFETCH(0);

  for (int kt = 0; kt < 16; kt++) {
    __syncthreads();  // B0: all waves done reading staged buffers (prev iter)
    *(uint4*)&ldsK[oKA] = pk0;
    *(uint4*)&ldsK[oKB] = pk1;
    *(uint4*)&ldsRK[oRKA] = prk0;
    *(uint4*)&ldsRK[oRKB] = prk1;
    *(uint4*)&ldsRK[oRKC] = prk2;
    *(uint4*)&ldsRK[oRKD] = prk3;
    *(uint4*)&ldsV[oKA] = pv0;
    *(uint4*)&ldsV[oKB] = pv1;
    *(uint4*)&ldsRV[oRVA] = prv0;
    *(uint4*)&ldsRV[oRVB] = prv1;
    *(uint4*)&ldsRV[oRVC] = prv2;
    *(uint4*)&ldsRV[oRVD] = prv3;
    __syncthreads();  // B1: staged tiles visible to all waves

    // issue next iteration's global loads; latency hides under this iter's compute
    if (kt < 15) PREFETCH((kt + 1) * 64);

    // S = Q*(K/8)^T ; QR[l,c] = Q[l,:].relK[base+c,:]
    f32x4 sacc[4], qracc[8];
#pragma unroll
    for (int cf = 0; cf < 4; cf++) sacc[cf] = (f32x4){0.f, 0.f, 0.f, 0.f};
#pragma unroll
    for (int cf = 0; cf < 8; cf++) qracc[cf] = (f32x4){0.f, 0.f, 0.f, 0.f};
#pragma unroll
    for (int ks = 0; ks < 2; ks++) {
      f16x8 qf = ks ? qf1 : qf0;
#pragma unroll
      for (int cf = 0; cf < 4; cf++) {
        f16x8 kf = *(const f16x8*)&ldsK[(cf * 16 + l15) * 72 + ks * 32 + hi * 8];
        sacc[cf] = mfma16(qf, kf, sacc[cf]);
      }
#pragma unroll
      for (int cf = 0; cf < 8; cf++) {
        f16x8 rf = *(const f16x8*)&ldsRK[(cf * 16 + l15) * 72 + ks * 32 + hi * 8];
        qracc[cf] = mfma16(qf, rf, qracc[cf]);
      }
    }
    // write QR (own 16 rows only -> intra-wave, no barrier)
#pragma unroll
    for (int cf = 0; cf < 8; cf++)
#pragma unroll
      for (int i = 0; i < 4; i++)
        ldsQR[(w * 16 + hi * 4 + i) * 136 + cf * 16 + l15] = (f16)qracc[cf][i];
    asm volatile("s_waitcnt lgkmcnt(0)" ::: "memory");  // QR visible to own wave

    // gather rel scores (diagonal, own rows) in place, then online softmax
#pragma unroll
    for (int cf = 0; cf < 4; cf++)
#pragma unroll
      for (int i = 0; i < 4; i++) {
        int li = w * 16 + hi * 4 + i;
        int ri = cf * 16 + l15;
        sacc[cf][i] += (float)ldsQR[li * 136 + 63 + ri - li];
      }
    float rmax[4];
#pragma unroll
    for (int i = 0; i < 4; i++)
      rmax[i] = fmaxf(fmaxf(sacc[0][i], sacc[1][i]), fmaxf(sacc[2][i], sacc[3][i]));
#pragma unroll
    for (int m = 1; m < 16; m <<= 1)
#pragma unroll
      for (int i = 0; i < 4; i++) rmax[i] = fmaxf(rmax[i], __shfl_xor(rmax[i], m, 64));
    float rsum[4];
#pragma unroll
    for (int i = 0; i < 4; i++) {
      float mn = fmaxf(mrow[i], rmax[i]);
      float al = __expf(mrow[i] - mn);
      mrow[i] = mn;
      lsum[i] *= al;
#pragma unroll
      for (int cf = 0; cf < 4; cf++) acc_o[cf][i] *= al;
      rsum[i] = 0.f;
    }
#pragma unroll
    for (int cf = 0; cf < 4; cf++)
#pragma unroll
      for (int i = 0; i < 4; i++) {
        float p = __expf(sacc[cf][i] - mrow[i]);
        sacc[cf][i] = p;  // in place: sacc now holds P
        rsum[i] += p;
      }
#pragma unroll
    for (int m = 1; m < 16; m <<= 1)
#pragma unroll
      for (int i = 0; i < 4; i++) rsum[i] += __shfl_xor(rsum[i], m, 64);
#pragma unroll
    for (int i = 0; i < 4; i++) lsum[i] += rsum[i];

    // all gather reads retired; safe to overwrite QR with Pskew
    asm volatile("s_waitcnt lgkmcnt(0)" ::: "memory");
    // zero own Pskew rows (cols 0..127), then scatter P into Pmain+Pskew
    const uint4 z4 = make_uint4(0u, 0u, 0u, 0u);
#pragma unroll
    for (int s = 0; s < 4; s++) {
      int tau = lane + 64 * s;  // 16 rows * 16 chunks
      int rr = w * 16 + (tau >> 4), cc = (tau & 15) * 8;
      *(uint4*)&ldsQR[rr * 136 + cc] = z4;
    }
#pragma unroll
    for (int cf = 0; cf < 4; cf++)
#pragma unroll
      for (int i = 0; i < 4; i++) {
        int li = w * 16 + hi * 4 + i;
        int ri = cf * 16 + l15;
        f16 ph = (f16)sacc[cf][i];
        ldsP[li * 72 + ri] = ph;
        ldsQR[li * 136 + 63 + ri - li] = ph;  // skew: col = 63 + r - l
      }
    asm volatile("s_waitcnt lgkmcnt(0)" ::: "memory");  // P visible to own wave

    // O += P @ V  (B-frag rows = d from V^T tile)
#pragma unroll
    for (int ks = 0; ks < 2; ks++) {
      f16x8 pa = *(const f16x8*)&ldsP[(w * 16 + l15) * 72 + ks * 32 + hi * 8];
#pragma unroll
      for (int cf = 0; cf < 4; cf++) {
        f16x8 vb = *(const f16x8*)&ldsV[(cf * 16 + l15) * 72 + ks * 32 + hi * 8];
        acc_o[cf] = mfma16(pa, vb, acc_o[cf]);
      }
    }
    // O += Pskew @ relV_band  (K-dim = 128)
#pragma unroll
    for (int ks = 0; ks < 4; ks++) {
      f16x8 pa = *(const f16x8*)&ldsQR[(w * 16 + l15) * 136 + ks * 32 + hi * 8];
#pragma unroll
      for (int cf = 0; cf < 4; cf++) {
        f16x8 rb = *(const f16x8*)&ldsRV[(cf * 16 + l15) * 136 + ks * 32 + hi * 8];
        acc_o[cf] = mfma16(pa, rb, acc_o[cf]);
      }
    }
  }
  // epilogue: normalize, store fp16 to AO[b*1024+l][h*64+d]
#pragma unroll
  for (int cf = 0; cf < 4; cf++)
#pragma unroll
    for (int i = 0; i < 4; i++) {
      float v = acc_o[cf][i] / lsum[i];
      AO[((long)(b * 1024 + l0 + w * 16 + hi * 4 + i)) * 1024 + h * 64 + cf * 16 + l15] =
          (f16)v;
    }
}

// ---------------- launch ----------------
extern "C" void kernel_launch(void* const* d_in, const int* in_sizes, int n_in,
                              void* d_out, int out_size, void* d_ws, size_t ws_size,
                              hipStream_t stream) {
  const float* x = (const float*)d_in[0];
  const float* Wq = (const float*)d_in[1];
  const float* bq = (const float*)d_in[2];
  const float* Wk = (const float*)d_in[3];
  const float* bk = (const float*)d_in[4];
  const float* Wv = (const float*)d_in[5];
  const float* bv = (const float*)d_in[6];
  const float* Wo = (const float*)d_in[7];
  const float* bo = (const float*)d_in[8];
  const float* relk = (const float*)d_in[9];
  const float* relv = (const float*)d_in[10];
  float* out = (float*)d_out;

  char* ws = (char*)d_ws;
  size_t off = 0;
  auto alloc = [&](size_t bytes) {
    char* p = ws + off;
    off += (bytes + 255) & ~(size_t)255;
    return p;
  };
  f16* xh = (f16*)alloc(8192ull * 1024 * 2);
  f16* Wqh = (f16*)alloc(1024ull * 1024 * 2);
  f16* Wkh = (f16*)alloc(1024ull * 1024 * 2);
  f16* Wvh = (f16*)alloc(1024ull * 1024 * 2);
  f16* Woh = (f16*)alloc(1024ull * 1024 * 2);
  f16* relKh = (f16*)alloc(2048ull * 64 * 2);
  f16* relVTh = (f16*)alloc(64ull * 2048 * 2);
  f16* Qh = (f16*)alloc(8192ull * 1024 * 2);
  f16* Kh = (f16*)alloc(8192ull * 1024 * 2);
  f16* Vth = (f16*)alloc(1024ull * 8192 * 2);
  f16* AOh = (f16*)alloc(8192ull * 1024 * 2);
  if (ws_size < off) return;  // workspace too small: fail loudly at validation

  pack_f16_kernel<<<32768, 256, 0, stream>>>(x, xh, 8192 * 1024);
  pack_f16_kernel<<<4096, 256, 0, stream>>>(Wq, Wqh, 1024 * 1024);
  pack_f16_kernel<<<4096, 256, 0, stream>>>(Wk, Wkh, 1024 * 1024);
  pack_f16_kernel<<<4096, 256, 0, stream>>>(Wv, Wvh, 1024 * 1024);
  pack_f16_kernel<<<4096, 256, 0, stream>>>(Wo, Woh, 1024 * 1024);
  pack_relk_kernel<<<512, 256, 0, stream>>>(relk, relKh);
  pack_relvt_kernel<<<512, 256, 0, stream>>>(relv, relVTh);

  dim3 g1(8, 64);  // N/128, M/128
  gemm_bt<0, 0><<<g1, 256, 0, stream>>>(xh, Wqh, bq, Qh, 8192, 1024, 1024, 1.0f);
  gemm_bt<0, 0><<<g1, 256, 0, stream>>>(xh, Wkh, bk, Kh, 8192, 1024, 1024, 0.125f);
  dim3 g2(64, 8);  // V^T = Wv @ x^T : M=1024, N=8192
  gemm_bt<0, 1><<<g2, 256, 0, stream>>>(Wvh, xh, bv, Vth, 1024, 8192, 1024, 1.0f);

  attn_kernel<<<2048, 256, 0, stream>>>(Qh, Kh, Vth, relKh, relVTh, AOh);

  gemm_bt<1, 0><<<g1, 256, 0, stream>>>(AOh, Woh, bo, out, 8192, 1024, 1024, 1.0f);
}

// Round 4
// 403.542 us; speedup vs baseline: 1.5807x; 1.0499x over previous
//
#include <hip/hip_runtime.h>

typedef _Float16 f16;
typedef _Float16 f16x8 __attribute__((ext_vector_type(8)));
typedef float f32x4 __attribute__((ext_vector_type(4)));

static __device__ __forceinline__ f32x4 mfma16(f16x8 a, f16x8 b, f32x4 c) {
  return __builtin_amdgcn_mfma_f32_16x16x32_f16(a, b, c, 0, 0, 0);
}

// ---------------- pack kernels ----------------
__global__ void pack_f16_kernel(const float* __restrict__ s, f16* __restrict__ d, int n) {
  int i = blockIdx.x * 256 + threadIdx.x;
  if (i < n) d[i] = (f16)s[i];
}

// relK padded: row 2047 -> 0
__global__ void pack_relk_kernel(const float* __restrict__ relk, f16* __restrict__ dst) {
  int idx = blockIdx.x * 256 + threadIdx.x;  // 2048*64
  dst[idx] = (idx < 2047 * 64) ? (f16)relk[idx] : (f16)0.f;
}

// relVT[d][p] = relative_v[p][d], padded col p==2047 -> 0
__global__ void pack_relvt_kernel(const float* __restrict__ relv, f16* __restrict__ dst) {
  int idx = blockIdx.x * 256 + threadIdx.x;  // 64*2048 threads
  int dd = idx >> 11, p = idx & 2047;
  dst[idx] = (p < 2047) ? (f16)relv[p * 64 + dd] : (f16)0.f;
}

// ---------------- generic B^T GEMM: C[i,j] = (sum_k A[i,k]*B[j,k] + bias)*oscale ----
template <int OUT_F32, int BIAS_ROW>
__global__ __launch_bounds__(256, 2) void gemm_bt(
    const f16* __restrict__ A, const f16* __restrict__ B,
    const float* __restrict__ bias, void* __restrict__ Cout,
    int M, int N, int Kd, float oscale) {
  __shared__ __align__(16) f16 Al[128 * 72];
  __shared__ __align__(16) f16 Bl[128 * 72];
  const int tid = threadIdx.x;
  const int w = tid >> 6, lane = tid & 63;
  const int l15 = lane & 15, hi = lane >> 4;
  const long i0 = (long)blockIdx.y * 128, j0 = (long)blockIdx.x * 128;
  const int wr = (w >> 1) * 64, wc = (w & 1) * 64;

  f32x4 acc[4][4];
#pragma unroll
  for (int a = 0; a < 4; a++)
#pragma unroll
    for (int b2 = 0; b2 < 4; b2++) acc[a][b2] = (f32x4){0.f, 0.f, 0.f, 0.f};

  for (int k0 = 0; k0 < Kd; k0 += 64) {
    __syncthreads();
#pragma unroll
    for (int s = 0; s < 4; s++) {
      int tau = tid + 256 * s;
      int r = tau >> 3, c = (tau & 7) * 8;
      *(uint4*)&Al[r * 72 + c] = *(const uint4*)(A + (i0 + r) * Kd + k0 + c);
      *(uint4*)&Bl[r * 72 + c] = *(const uint4*)(B + (j0 + r) * Kd + k0 + c);
    }
    __syncthreads();
#pragma unroll
    for (int ks = 0; ks < 2; ks++) {
      f16x8 af[4], bf[4];
#pragma unroll
      for (int mb = 0; mb < 4; mb++)
        af[mb] = *(const f16x8*)&Al[(wr + mb * 16 + l15) * 72 + ks * 32 + hi * 8];
#pragma unroll
      for (int nb = 0; nb < 4; nb++)
        bf[nb] = *(const f16x8*)&Bl[(wc + nb * 16 + l15) * 72 + ks * 32 + hi * 8];
#pragma unroll
      for (int mb = 0; mb < 4; mb++)
#pragma unroll
        for (int nb = 0; nb < 4; nb++) acc[mb][nb] = mfma16(af[mb], bf[nb], acc[mb][nb]);
    }
  }
#pragma unroll
  for (int mb = 0; mb < 4; mb++) {
#pragma unroll
    for (int nb = 0; nb < 4; nb++) {
      long row = i0 + wr + mb * 16 + hi * 4;
      long col = j0 + wc + nb * 16 + l15;
      float bc = BIAS_ROW ? 0.f : bias[col];
#pragma unroll
      for (int i = 0; i < 4; i++) {
        float v = acc[mb][nb][i] + (BIAS_ROW ? bias[row + i] : bc);
        v *= oscale;
        if (OUT_F32)
          ((float*)Cout)[(row + i) * N + col] = v;
        else
          ((f16*)Cout)[(row + i) * N + col] = (f16)v;
      }
    }
  }
}

// ---------------- fused relative-position flash attention ----------------
// 1D grid 2048 = 16 qtiles x 128 b*h, XCD-swizzled. 4 waves, BM=BN=64.
// LDS 54,272 B -> 3 blocks/CU (12 waves). 3 barriers/iter:
//  B0 -> stage K,RK,V,RV -> B1 -> QK MFMAs (read K,RK) -> B2
//  -> QR/Pskew/Pmain overwrite the K/RK region (intra-wave) -> PV MFMAs.
// Per-wave band narrowing: wave w only needs rel-band cols [48-16w, 126-16w]
//  -> QK-rel uses 5 16-col chunks (base 3-w), PV-skew uses 3 32-col chunks
//  (base co = w<2 ? 32 : 0).
#define PREFETCH(R0N)                                    \
  do {                                                   \
    pk0 = *(const uint4*)(kpA + (long)(R0N) * 1024);     \
    pk1 = *(const uint4*)(kpB + (long)(R0N) * 1024);     \
    prk0 = *(const uint4*)(rkpA + (R0N) * 64);           \
    prk1 = *(const uint4*)(rkpB + (R0N) * 64);           \
    prk2 = *(const uint4*)(rkpC + (R0N) * 64);           \
    prk3 = *(const uint4*)(rkpD + (R0N) * 64);           \
    pv0 = *(const uint4*)(vpA + (R0N));                  \
    pv1 = *(const uint4*)(vpB + (R0N));                  \
    prv0 = *(const uint4*)(rvpA + (R0N));                \
    prv1 = *(const uint4*)(rvpB + (R0N));                \
    prv2 = *(const uint4*)(rvpC + (R0N));                \
    prv3 = *(const uint4*)(rvpD + (R0N));                \
  } while (0)

__global__ __launch_bounds__(256, 3) void attn_kernel(
    const f16* __restrict__ Qh, const f16* __restrict__ Kh,
    const f16* __restrict__ Vth, const f16* __restrict__ relKh,
    const f16* __restrict__ relVTh, f16* __restrict__ AO) {
  // unified LDS, 27136 f16 = 54,272 B
  __shared__ __align__(16) f16 SH[27136];
  f16* const ldsK = SH;            // [64][72]  (staging phase)
  f16* const ldsRK = SH + 4608;    // [128][72] (staging phase)
  f16* const ldsQR = SH;           // [64][136] alias: QR then Pskew
  f16* const ldsP = SH + 8704;     // [64][72]  alias: Pmain
  f16* const ldsV = SH + 13824;    // [64][72]
  f16* const ldsRV = SH + 18432;   // [64][136]

  const int tid = threadIdx.x;
  const int w = tid >> 6, lane = tid & 63;
  const int l15 = lane & 15, hi = lane >> 4;
  // XCD swizzle: 16 q-tiles of one (b,h) land on one XCD, temporally adjacent
  const int flat = blockIdx.x;
  const int xcd = flat & 7, slot = flat >> 3;
  const int bh = xcd * 16 + (slot >> 4);
  const int qt = slot & 15;
  const int b = bh >> 4, h = bh & 15;
  const int l0 = qt * 64;
  const int cfb = 3 - w;               // QK-rel chunk base (5 chunks)
  const int co = (w < 2) ? 32 : 0;     // PV-skew col offset (3 chunks)

  // per-thread staging geometry
  const int t3 = tid >> 3, c8 = (tid & 7) * 8;
  const int t4 = tid >> 4, c16 = (tid & 15) * 8;
  const f16* kpA = Kh + ((long)(b * 1024 + t3)) * 1024 + h * 64 + c8;
  const f16* kpB = kpA + 32l * 1024;
  const f16* rkpA = relKh + (long)(960 - l0 + t3) * 64 + c8;
  const f16* rkpB = rkpA + 32l * 64;
  const f16* rkpC = rkpA + 64l * 64;
  const f16* rkpD = rkpA + 96l * 64;
  const f16* vpA = Vth + ((long)(h * 64 + t3)) * 8192 + b * 1024 + c8;
  const f16* vpB = vpA + 32l * 8192;
  const f16* rvpA = relVTh + (long)t4 * 2048 + (960 - l0) + c16;
  const f16* rvpB = rvpA + 16l * 2048;
  const f16* rvpC = rvpA + 32l * 2048;
  const f16* rvpD = rvpA + 48l * 2048;
  // LDS write offsets
  const int oKA = t3 * 72 + c8, oKB = (t3 + 32) * 72 + c8;
  const int oRKC = (t3 + 64) * 72 + c8, oRKD = (t3 + 96) * 72 + c8;
  const int oRVA = t4 * 136 + c16, oRVB = (t4 + 16) * 136 + c16,
            oRVC = (t4 + 32) * 136 + c16, oRVD = (t4 + 48) * 136 + c16;

  // Q fragments (row = l0 + 16w + l15), k-halves ks=0,1
  const long qoff = ((long)(b * 1024 + l0 + w * 16 + l15)) * 1024 + h * 64 + hi * 8;
  const f16x8 qf0 = *(const f16x8*)(Qh + qoff);
  const f16x8 qf1 = *(const f16x8*)(Qh + qoff + 32);

  f32x4 acc_o[4];
#pragma unroll
  for (int cf = 0; cf < 4; cf++) acc_o[cf] = (f32x4){0.f, 0.f, 0.f, 0.f};
  float mrow[4] = {-1e30f, -1e30f, -1e30f, -1e30f};
  float lsum[4] = {0.f, 0.f, 0.f, 0.f};

  uint4 pk0, pk1, prk0, prk1, prk2, prk3, pv0, pv1, prv0, prv1, prv2, prv3;
  PREFETCH(0);

  for (int kt = 0; kt < 16; kt++) {
    __syncthreads();  // B0: all waves done with PV reads of prev iter
    *(uint4*)&ldsK[oKA] = pk0;
    *(uint4*)&ldsK[oKB] = pk1;
    *(uint4*)&ldsRK[oKA] = prk0;
    *(uint4*)&ldsRK[oKB] = prk1;
    *(uint4*)&ldsRK[oRKC] = prk2;
    *(uint4*)&ldsRK[oRKD] = prk3;
    *(uint4*)&ldsV[oKA] = pv0;
    *(uint4*)&ldsV[oKB] = pv1;
    *(uint4*)&ldsRV[oRVA] = prv0;
    *(uint4*)&ldsRV[oRVB] = prv1;
    *(uint4*)&ldsRV[oRVC] = prv2;
    *(uint4*)&ldsRV[oRVD] = prv3;
    __syncthreads();  // B1: staged tiles visible to all waves

    // issue next iteration's global loads; latency hides under this iter
    if (kt < 15) PREFETCH((kt + 1) * 64);

    // S = Q*(K/8)^T (4 chunks) ; QR = Q·relK over 5 narrowed chunks
    f32x4 sacc[4], qracc[5];
#pragma unroll
    for (int cf = 0; cf < 4; cf++) sacc[cf] = (f32x4){0.f, 0.f, 0.f, 0.f};
#pragma unroll
    for (int j = 0; j < 5; j++) qracc[j] = (f32x4){0.f, 0.f, 0.f, 0.f};
    __builtin_amdgcn_s_setprio(1);
#pragma unroll
    for (int ks = 0; ks < 2; ks++) {
      f16x8 qf = ks ? qf1 : qf0;
#pragma unroll
      for (int cf = 0; cf < 4; cf++) {
        f16x8 kf = *(const f16x8*)&ldsK[(cf * 16 + l15) * 72 + ks * 32 + hi * 8];
        sacc[cf] = mfma16(qf, kf, sacc[cf]);
      }
#pragma unroll
      for (int j = 0; j < 5; j++) {
        f16x8 rf = *(const f16x8*)&ldsRK[((cfb + j) * 16 + l15) * 72 + ks * 32 + hi * 8];
        qracc[j] = mfma16(qf, rf, qracc[j]);
      }
    }
    __builtin_amdgcn_s_setprio(0);
    __syncthreads();  // B2: all QK reads of K/RK done -> region reusable

    // write QR into aliased region (own 16 rows; intra-wave from here on)
#pragma unroll
    for (int j = 0; j < 5; j++)
#pragma unroll
      for (int i = 0; i < 4; i++)
        ldsQR[(w * 16 + hi * 4 + i) * 136 + (cfb + j) * 16 + l15] = (f16)qracc[j][i];
    asm volatile("s_waitcnt lgkmcnt(0)" ::: "memory");

    // gather rel scores (diagonal, own rows) in place, then online softmax
#pragma unroll
    for (int cf = 0; cf < 4; cf++)
#pragma unroll
      for (int i = 0; i < 4; i++) {
        int li = w * 16 + hi * 4 + i;
        int ri = cf * 16 + l15;
        sacc[cf][i] += (float)ldsQR[li * 136 + 63 + ri - li];
      }
    float rmax[4];
#pragma unroll
    for (int i = 0; i < 4; i++)
      rmax[i] = fmaxf(fmaxf(sacc[0][i], sacc[1][i]), fmaxf(sacc[2][i], sacc[3][i]));
#pragma unroll
    for (int m = 1; m < 16; m <<= 1)
#pragma unroll
      for (int i = 0; i < 4; i++) rmax[i] = fmaxf(rmax[i], __shfl_xor(rmax[i], m, 64));
    // defer-max: only rescale when the running max grew by > 8
    {
      bool big = false;
#pragma unroll
      for (int i = 0; i < 4; i++) big |= rmax[i] > mrow[i] + 8.f;
      if (__any(big)) {
#pragma unroll
        for (int i = 0; i < 4; i++) {
          float mn = fmaxf(mrow[i], rmax[i]);
          float al = __expf(mrow[i] - mn);
          mrow[i] = mn;
          lsum[i] *= al;
#pragma unroll
          for (int cf = 0; cf < 4; cf++) acc_o[cf][i] *= al;
        }
      }
    }
    float rsum[4] = {0.f, 0.f, 0.f, 0.f};
#pragma unroll
    for (int cf = 0; cf < 4; cf++)
#pragma unroll
      for (int i = 0; i < 4; i++) {
        float p = __expf(sacc[cf][i] - mrow[i]);
        sacc[cf][i] = p;  // in place: sacc now holds P (<= e^8)
        rsum[i] += p;
      }
#pragma unroll
    for (int m = 1; m < 16; m <<= 1)
#pragma unroll
      for (int i = 0; i < 4; i++) rsum[i] += __shfl_xor(rsum[i], m, 64);
#pragma unroll
    for (int i = 0; i < 4; i++) lsum[i] += rsum[i];

    // all gather reads retired; overwrite QR rows with Pskew
    asm volatile("s_waitcnt lgkmcnt(0)" ::: "memory");
    const uint4 z4 = make_uint4(0u, 0u, 0u, 0u);
#pragma unroll
    for (int s = 0; s < 4; s++) {
      int tau = lane + 64 * s;  // 16 rows * 16 chunks
      int rr = w * 16 + (tau >> 4), cc = (tau & 15) * 8;
      *(uint4*)&ldsQR[rr * 136 + cc] = z4;
    }
#pragma unroll
    for (int cf = 0; cf < 4; cf++)
#pragma unroll
      for (int i = 0; i < 4; i++) {
        int li = w * 16 + hi * 4 + i;
        int ri = cf * 16 + l15;
        f16 ph = (f16)sacc[cf][i];
        ldsP[li * 72 + ri] = ph;
        ldsQR[li * 136 + 63 + ri - li] = ph;  // skew: col = 63 + r - l
      }
    asm volatile("s_waitcnt lgkmcnt(0)" ::: "memory");  // P visible to own wave

    __builtin_amdgcn_s_setprio(1);
    // O += P @ V  (B-frag rows = d from V^T tile)
#pragma unroll
    for (int ks = 0; ks < 2; ks++) {
      f16x8 pa = *(const f16x8*)&ldsP[(w * 16 + l15) * 72 + ks * 32 + hi * 8];
#pragma unroll
      for (int cf = 0; cf < 4; cf++) {
        f16x8 vb = *(const f16x8*)&ldsV[(cf * 16 + l15) * 72 + ks * 32 + hi * 8];
        acc_o[cf] = mfma16(pa, vb, acc_o[cf]);
      }
    }
    // O += Pskew @ relV_band, narrowed to 3 chunks at col offset co
#pragma unroll
    for (int ks = 0; ks < 3; ks++) {
      f16x8 pa = *(const f16x8*)&ldsQR[(w * 16 + l15) * 136 + co + ks * 32 + hi * 8];
#pragma unroll
      for (int cf = 0; cf < 4; cf++) {
        f16x8 rb = *(const f16x8*)&ldsRV[(cf * 16 + l15) * 136 + co + ks * 32 + hi * 8];
        acc_o[cf] = mfma16(pa, rb, acc_o[cf]);
      }
    }
    __builtin_amdgcn_s_setprio(0);
  }
  // epilogue: normalize, store fp16 to AO[b*1024+l][h*64+d]
#pragma unroll
  for (int cf = 0; cf < 4; cf++)
#pragma unroll
    for (int i = 0; i < 4; i++) {
      float v = acc_o[cf][i] / lsum[i];
      AO[((long)(b * 1024 + l0 + w * 16 + hi * 4 + i)) * 1024 + h * 64 + cf * 16 + l15] =
          (f16)v;
    }
}

// ---------------- launch ----------------
extern "C" void kernel_launch(void* const* d_in, const int* in_sizes, int n_in,
                              void* d_out, int out_size, void* d_ws, size_t ws_size,
                              hipStream_t stream) {
  const float* x = (const float*)d_in[0];
  const float* Wq = (const float*)d_in[1];
  const float* bq = (const float*)d_in[2];
  const float* Wk = (const float*)d_in[3];
  const float* bk = (const float*)d_in[4];
  const float* Wv = (const float*)d_in[5];
  const float* bv = (const float*)d_in[6];
  const float* Wo = (const float*)d_in[7];
  const float* bo = (const float*)d_in[8];
  const float* relk = (const float*)d_in[9];
  const float* relv = (const float*)d_in[10];
  float* out = (float*)d_out;

  char* ws = (char*)d_ws;
  size_t off = 0;
  auto alloc = [&](size_t bytes) {
    char* p = ws + off;
    off += (bytes + 255) & ~(size_t)255;
    return p;
  };
  f16* xh = (f16*)alloc(8192ull * 1024 * 2);
  f16* Wqh = (f16*)alloc(1024ull * 1024 * 2);
  f16* Wkh = (f16*)alloc(1024ull * 1024 * 2);
  f16* Wvh = (f16*)alloc(1024ull * 1024 * 2);
  f16* Woh = (f16*)alloc(1024ull * 1024 * 2);
  f16* relKh = (f16*)alloc(2048ull * 64 * 2);
  f16* relVTh = (f16*)alloc(64ull * 2048 * 2);
  f16* Qh = (f16*)alloc(8192ull * 1024 * 2);
  f16* Kh = (f16*)alloc(8192ull * 1024 * 2);
  f16* Vth = (f16*)alloc(1024ull * 8192 * 2);
  f16* AOh = (f16*)alloc(8192ull * 1024 * 2);
  if (ws_size < off) return;  // workspace too small: fail loudly at validation

  pack_f16_kernel<<<32768, 256, 0, stream>>>(x, xh, 8192 * 1024);
  pack_f16_kernel<<<4096, 256, 0, stream>>>(Wq, Wqh, 1024 * 1024);
  pack_f16_kernel<<<4096, 256, 0, stream>>>(Wk, Wkh, 1024 * 1024);
  pack_f16_kernel<<<4096, 256, 0, stream>>>(Wv, Wvh, 1024 * 1024);
  pack_f16_kernel<<<4096, 256, 0, stream>>>(Wo, Woh, 1024 * 1024);
  pack_relk_kernel<<<512, 256, 0, stream>>>(relk, relKh);
  pack_relvt_kernel<<<512, 256, 0, stream>>>(relv, relVTh);

  dim3 g1(8, 64);  // N/128, M/128
  gemm_bt<0, 0><<<g1, 256, 0, stream>>>(xh, Wqh, bq, Qh, 8192, 1024, 1024, 1.0f);
  gemm_bt<0, 0><<<g1, 256, 0, stream>>>(xh, Wkh, bk, Kh, 8192, 1024, 1024, 0.125f);
  dim3 g2(64, 8);  // V^T = Wv @ x^T : M=1024, N=8192
  gemm_bt<0, 1><<<g2, 256, 0, stream>>>(Wvh, xh, bv, Vth, 1024, 8192, 1024, 1.0f);

  attn_kernel<<<2048, 256, 0, stream>>>(Qh, Kh, Vth, relKh, relVTh, AOh);

  gemm_bt<1, 0><<<g1, 256, 0, stream>>>(AOh, Woh, bo, out, 8192, 1024, 1024, 1.0f);
}

// Round 6
// 375.982 us; speedup vs baseline: 1.6965x; 1.0733x over previous
//
#include <hip/hip_runtime.h>

typedef _Float16 f16;
typedef _Float16 f16x2 __attribute__((ext_vector_type(2)));
typedef _Float16 f16x8 __attribute__((ext_vector_type(8)));
typedef float f32x4 __attribute__((ext_vector_type(4)));

static __device__ __forceinline__ f32x4 mfma16(f16x8 a, f16x8 b, f32x4 c) {
  return __builtin_amdgcn_mfma_f32_16x16x32_f16(a, b, c, 0, 0, 0);
}

// ---------------- pack kernels ----------------
__global__ void pack_f16_kernel(const float* __restrict__ s, f16* __restrict__ d, int n) {
  int i = blockIdx.x * 256 + threadIdx.x;
  if (i < n) d[i] = (f16)s[i];
}

// relK padded: row 2047 -> 0
__global__ void pack_relk_kernel(const float* __restrict__ relk, f16* __restrict__ dst) {
  int idx = blockIdx.x * 256 + threadIdx.x;  // 2048*64
  dst[idx] = (idx < 2047 * 64) ? (f16)relk[idx] : (f16)0.f;
}

// relVT[d][p] = relative_v[p][d], padded col p==2047 -> 0
__global__ void pack_relvt_kernel(const float* __restrict__ relv, f16* __restrict__ dst) {
  int idx = blockIdx.x * 256 + threadIdx.x;  // 64*2048 threads
  int dd = idx >> 11, p = idx & 2047;
  dst[idx] = (p < 2047) ? (f16)relv[p * 64 + dd] : (f16)0.f;
}

// ---------------- generic B^T GEMM: C[i,j] = (sum_k A[i,k]*B[j,k] + bias)*oscale ----
template <int OUT_F32, int BIAS_ROW>
__global__ __launch_bounds__(256, 2) void gemm_bt(
    const f16* __restrict__ A, const f16* __restrict__ B,
    const float* __restrict__ bias, void* __restrict__ Cout,
    int M, int N, int Kd, float oscale) {
  __shared__ __align__(16) f16 Al[128 * 72];
  __shared__ __align__(16) f16 Bl[128 * 72];
  const int tid = threadIdx.x;
  const int w = tid >> 6, lane = tid & 63;
  const int l15 = lane & 15, hi = lane >> 4;
  const long i0 = (long)blockIdx.y * 128, j0 = (long)blockIdx.x * 128;
  const int wr = (w >> 1) * 64, wc = (w & 1) * 64;

  f32x4 acc[4][4];
#pragma unroll
  for (int a = 0; a < 4; a++)
#pragma unroll
    for (int b2 = 0; b2 < 4; b2++) acc[a][b2] = (f32x4){0.f, 0.f, 0.f, 0.f};

  for (int k0 = 0; k0 < Kd; k0 += 64) {
    __syncthreads();
#pragma unroll
    for (int s = 0; s < 4; s++) {
      int tau = tid + 256 * s;
      int r = tau >> 3, c = (tau & 7) * 8;
      *(uint4*)&Al[r * 72 + c] = *(const uint4*)(A + (i0 + r) * Kd + k0 + c);
      *(uint4*)&Bl[r * 72 + c] = *(const uint4*)(B + (j0 + r) * Kd + k0 + c);
    }
    __syncthreads();
#pragma unroll
    for (int ks = 0; ks < 2; ks++) {
      f16x8 af[4], bf[4];
#pragma unroll
      for (int mb = 0; mb < 4; mb++)
        af[mb] = *(const f16x8*)&Al[(wr + mb * 16 + l15) * 72 + ks * 32 + hi * 8];
#pragma unroll
      for (int nb = 0; nb < 4; nb++)
        bf[nb] = *(const f16x8*)&Bl[(wc + nb * 16 + l15) * 72 + ks * 32 + hi * 8];
#pragma unroll
      for (int mb = 0; mb < 4; mb++)
#pragma unroll
        for (int nb = 0; nb < 4; nb++) acc[mb][nb] = mfma16(af[mb], bf[nb], acc[mb][nb]);
    }
  }
#pragma unroll
  for (int mb = 0; mb < 4; mb++) {
#pragma unroll
    for (int nb = 0; nb < 4; nb++) {
      long row = i0 + wr + mb * 16 + hi * 4;
      long col = j0 + wc + nb * 16 + l15;
      float bc = BIAS_ROW ? 0.f : bias[col];
#pragma unroll
      for (int i = 0; i < 4; i++) {
        float v = acc[mb][nb][i] + (BIAS_ROW ? bias[row + i] : bc);
        v *= oscale;
        if (OUT_F32)
          ((float*)Cout)[(row + i) * N + col] = v;
        else
          ((f16*)Cout)[(row + i) * N + col] = (f16)v;
      }
    }
  }
}

// ---------------- fused relative-position flash attention ----------------
// 1D grid 2048 = 16 qtiles x 128 b*h, XCD-swizzled. 4 waves, BM=BN=64.
// LDS 54,272 B. 3 barriers/iter. Register-pipelined global prefetch.
// This round: QR diagonal gather fully in-register (cvt_pk + ds_bpermute),
// row-sum via ones-MFMA, narrowed Pskew zero-fill. One lgkm drain per iter.
#define PREFETCH(R0N)                                    \
  do {                                                   \
    pk0 = *(const uint4*)(kpA + (long)(R0N) * 1024);     \
    pk1 = *(const uint4*)(kpB + (long)(R0N) * 1024);     \
    prk0 = *(const uint4*)(rkpA + (R0N) * 64);           \
    prk1 = *(const uint4*)(rkpB + (R0N) * 64);           \
    prk2 = *(const uint4*)(rkpC + (R0N) * 64);           \
    prk3 = *(const uint4*)(rkpD + (R0N) * 64);           \
    pv0 = *(const uint4*)(vpA + (R0N));                  \
    pv1 = *(const uint4*)(vpB + (R0N));                  \
    prv0 = *(const uint4*)(rvpA + (R0N));                \
    prv1 = *(const uint4*)(rvpB + (R0N));                \
    prv2 = *(const uint4*)(rvpC + (R0N));                \
    prv3 = *(const uint4*)(rvpD + (R0N));                \
  } while (0)

__global__ __launch_bounds__(256, 3) void attn_kernel(
    const f16* __restrict__ Qh, const f16* __restrict__ Kh,
    const f16* __restrict__ Vth, const f16* __restrict__ relKh,
    const f16* __restrict__ relVTh, f16* __restrict__ AO) {
  // unified LDS, 27136 f16 = 54,272 B
  __shared__ __align__(16) f16 SH[27136];
  f16* const ldsK = SH;           // [64][72]  (staging phase)
  f16* const ldsRK = SH + 4608;   // [128][72] (staging phase)
  f16* const ldsPS = SH;          // [64][136] alias: Pskew (after B2)
  f16* const ldsP = SH + 8704;    // [64][72]  alias: Pmain (after B2)
  f16* const ldsV = SH + 13824;   // [64][72]
  f16* const ldsRV = SH + 18432;  // [64][136]

  const int tid = threadIdx.x;
  const int w = tid >> 6, lane = tid & 63;
  const int l15 = lane & 15, hi = lane >> 4;
  // XCD swizzle: 16 q-tiles of one (b,h) land on one XCD, temporally adjacent
  const int flat = blockIdx.x;
  const int xcd = flat & 7, slot = flat >> 3;
  const int bh = xcd * 16 + (slot >> 4);
  const int qt = slot & 15;
  const int b = bh >> 4, h = bh & 15;
  const int l0 = qt * 64;
  const int cfb = 3 - w;            // QK-rel chunk base (5 chunks)
  const int co = (w < 2) ? 32 : 0;  // PV-skew col offset (3 chunks)

  // per-thread staging geometry
  const int t3 = tid >> 3, c8 = (tid & 7) * 8;
  const int t4 = tid >> 4, c16 = (tid & 15) * 8;
  const f16* kpA = Kh + ((long)(b * 1024 + t3)) * 1024 + h * 64 + c8;
  const f16* kpB = kpA + 32l * 1024;
  const f16* rkpA = relKh + (long)(960 - l0 + t3) * 64 + c8;
  const f16* rkpB = rkpA + 32l * 64;
  const f16* rkpC = rkpA + 64l * 64;
  const f16* rkpD = rkpA + 96l * 64;
  const f16* vpA = Vth + ((long)(h * 64 + t3)) * 8192 + b * 1024 + c8;
  const f16* vpB = vpA + 32l * 8192;
  const f16* rvpA = relVTh + (long)t4 * 2048 + (960 - l0) + c16;
  const f16* rvpB = rvpA + 16l * 2048;
  const f16* rvpC = rvpA + 32l * 2048;
  const f16* rvpD = rvpA + 48l * 2048;
  // LDS write offsets
  const int oKA = t3 * 72 + c8, oKB = (t3 + 32) * 72 + c8;
  const int oRKC = (t3 + 64) * 72 + c8, oRKD = (t3 + 96) * 72 + c8;
  const int oRVA = t4 * 136 + c16, oRVB = (t4 + 16) * 136 + c16,
            oRVC = (t4 + 32) * 136 + c16, oRVD = (t4 + 48) * 136 + c16;

  // Q fragments (row = l0 + 16w + l15), k-halves ks=0,1
  const long qoff = ((long)(b * 1024 + l0 + w * 16 + l15)) * 1024 + h * 64 + hi * 8;
  const f16x8 qf0 = *(const f16x8*)(Qh + qoff);
  const f16x8 qf1 = *(const f16x8*)(Qh + qoff + 32);

  const f16x8 ones1 = {(f16)1.f, (f16)1.f, (f16)1.f, (f16)1.f,
                       (f16)1.f, (f16)1.f, (f16)1.f, (f16)1.f};

  f32x4 acc_o[4];
#pragma unroll
  for (int cf = 0; cf < 4; cf++) acc_o[cf] = (f32x4){0.f, 0.f, 0.f, 0.f};
  float mrow[4] = {-1e30f, -1e30f, -1e30f, -1e30f};
  float lsum[4] = {0.f, 0.f, 0.f, 0.f};

  uint4 pk0, pk1, prk0, prk1, prk2, prk3, pv0, pv1, prv0, prv1, prv2, prv3;
  PREFETCH(0);

  for (int kt = 0; kt < 16; kt++) {
    __syncthreads();  // B0: all waves done with PV reads of prev iter
    *(uint4*)&ldsK[oKA] = pk0;
    *(uint4*)&ldsK[oKB] = pk1;
    *(uint4*)&ldsRK[oKA] = prk0;
    *(uint4*)&ldsRK[oKB] = prk1;
    *(uint4*)&ldsRK[oRKC] = prk2;
    *(uint4*)&ldsRK[oRKD] = prk3;
    *(uint4*)&ldsV[oKA] = pv0;
    *(uint4*)&ldsV[oKB] = pv1;
    *(uint4*)&ldsRV[oRVA] = prv0;
    *(uint4*)&ldsRV[oRVB] = prv1;
    *(uint4*)&ldsRV[oRVC] = prv2;
    *(uint4*)&ldsRV[oRVD] = prv3;
    __syncthreads();  // B1: staged tiles visible to all waves

    // issue next iteration's global loads; latency hides under this iter
    if (kt < 15) PREFETCH((kt + 1) * 64);

    // S = Q*(K/8)^T (4 chunks) ; QR = Q·relK over 5 narrowed chunks
    f32x4 sacc[4], qracc[5];
#pragma unroll
    for (int cf = 0; cf < 4; cf++) sacc[cf] = (f32x4){0.f, 0.f, 0.f, 0.f};
#pragma unroll
    for (int j = 0; j < 5; j++) qracc[j] = (f32x4){0.f, 0.f, 0.f, 0.f};
    __builtin_amdgcn_s_setprio(1);
#pragma unroll
    for (int ks = 0; ks < 2; ks++) {
      f16x8 qf = ks ? qf1 : qf0;
#pragma unroll
      for (int cf = 0; cf < 4; cf++) {
        f16x8 kf = *(const f16x8*)&ldsK[(cf * 16 + l15) * 72 + ks * 32 + hi * 8];
        sacc[cf] = mfma16(qf, kf, sacc[cf]);
      }
#pragma unroll
      for (int j = 0; j < 5; j++) {
        f16x8 rf = *(const f16x8*)&ldsRK[((cfb + j) * 16 + l15) * 72 + ks * 32 + hi * 8];
        qracc[j] = mfma16(qf, rf, qracc[j]);
      }
    }
    __builtin_amdgcn_s_setprio(0);
    __syncthreads();  // B2: all QK reads of K/RK done -> region reusable

    // in-register diagonal gather: rel[li][ri] lives in qracc chunk
    // cf + (t>>4) at lane hi*16 + (t&15), reg i, with t = 15 + l15 - (hi*4+i).
    // Pack chunk-pair as f16x2, one bpermute, select half.
#pragma unroll
    for (int i = 0; i < 4; i++) {
      int t = 15 + l15 - (hi * 4 + i);
      int idx = ((hi * 16) + (t & 15)) * 4;
      bool wrap = t >= 16;
#pragma unroll
      for (int cf = 0; cf < 4; cf++) {
        auto pk = __builtin_amdgcn_cvt_pkrtz(qracc[cf][i], qracc[cf + 1][i]);
        int g = __builtin_amdgcn_ds_bpermute(idx, __builtin_bit_cast(int, pk));
        f16x2 two = __builtin_bit_cast(f16x2, g);
        sacc[cf][i] += (float)(wrap ? two[1] : two[0]);
      }
    }

    // online softmax (row max over l15: 4 shfl rounds)
    float rmax[4];
#pragma unroll
    for (int i = 0; i < 4; i++)
      rmax[i] = fmaxf(fmaxf(sacc[0][i], sacc[1][i]), fmaxf(sacc[2][i], sacc[3][i]));
#pragma unroll
    for (int m = 1; m < 16; m <<= 1)
#pragma unroll
      for (int i = 0; i < 4; i++) rmax[i] = fmaxf(rmax[i], __shfl_xor(rmax[i], m, 64));
    // defer-max: only rescale when the running max grew by > 8
    {
      bool big = false;
#pragma unroll
      for (int i = 0; i < 4; i++) big |= rmax[i] > mrow[i] + 8.f;
      if (__any(big)) {
#pragma unroll
        for (int i = 0; i < 4; i++) {
          float mn = fmaxf(mrow[i], rmax[i]);
          float al = __expf(mrow[i] - mn);
          mrow[i] = mn;
          lsum[i] *= al;
#pragma unroll
          for (int cf = 0; cf < 4; cf++) acc_o[cf][i] *= al;
        }
      }
    }
#pragma unroll
    for (int cf = 0; cf < 4; cf++)
#pragma unroll
      for (int i = 0; i < 4; i++)
        sacc[cf][i] = __expf(sacc[cf][i] - mrow[i]);  // sacc now holds P (<= e^8)

    // zero only the PV-read window [co, co+96) of Pskew, then scatter P
    const uint4 z4 = make_uint4(0u, 0u, 0u, 0u);
#pragma unroll
    for (int s = 0; s < 3; s++) {
      int rr = w * 16 + (lane & 15);
      int cc = co + ((lane >> 4) + 4 * s) * 8;
      *(uint4*)&ldsPS[rr * 136 + cc] = z4;
    }
#pragma unroll
    for (int cf = 0; cf < 4; cf++)
#pragma unroll
      for (int i = 0; i < 4; i++) {
        int li = w * 16 + hi * 4 + i;
        int ri = cf * 16 + l15;
        f16 ph = (f16)sacc[cf][i];
        ldsP[li * 72 + ri] = ph;
        ldsPS[li * 136 + 63 + ri - li] = ph;  // skew: col = 63 + r - l
      }
    asm volatile("s_waitcnt lgkmcnt(0)" ::: "memory");  // P visible to own wave

    __builtin_amdgcn_s_setprio(1);
    // O += P @ V ; row-sums via ones-MFMA on the same pa fragments
    f32x4 rsacc = (f32x4){0.f, 0.f, 0.f, 0.f};
#pragma unroll
    for (int ks = 0; ks < 2; ks++) {
      f16x8 pa = *(const f16x8*)&ldsP[(w * 16 + l15) * 72 + ks * 32 + hi * 8];
      rsacc = mfma16(pa, ones1, rsacc);
#pragma unroll
      for (int cf = 0; cf < 4; cf++) {
        f16x8 vb = *(const f16x8*)&ldsV[(cf * 16 + l15) * 72 + ks * 32 + hi * 8];
        acc_o[cf] = mfma16(pa, vb, acc_o[cf]);
      }
    }
    // O += Pskew @ relV_band, narrowed to 3 chunks at col offset co
#pragma unroll
    for (int ks = 0; ks < 3; ks++) {
      f16x8 pa = *(const f16x8*)&ldsPS[(w * 16 + l15) * 136 + co + ks * 32 + hi * 8];
#pragma unroll
      for (int cf = 0; cf < 4; cf++) {
        f16x8 rb = *(const f16x8*)&ldsRV[(cf * 16 + l15) * 136 + co + ks * 32 + hi * 8];
        acc_o[cf] = mfma16(pa, rb, acc_o[cf]);
      }
    }
    __builtin_amdgcn_s_setprio(0);
#pragma unroll
    for (int i = 0; i < 4; i++) lsum[i] += rsacc[i];
  }
  // epilogue: normalize, store fp16 to AO[b*1024+l][h*64+d]
#pragma unroll
  for (int cf = 0; cf < 4; cf++)
#pragma unroll
    for (int i = 0; i < 4; i++) {
      float v = acc_o[cf][i] / lsum[i];
      AO[((long)(b * 1024 + l0 + w * 16 + hi * 4 + i)) * 1024 + h * 64 + cf * 16 + l15] =
          (f16)v;
    }
}

// ---------------- launch ----------------
extern "C" void kernel_launch(void* const* d_in, const int* in_sizes, int n_in,
                              void* d_out, int out_size, void* d_ws, size_t ws_size,
                              hipStream_t stream) {
  const float* x = (const float*)d_in[0];
  const float* Wq = (const float*)d_in[1];
  const float* bq = (const float*)d_in[2];
  const float* Wk = (const float*)d_in[3];
  const float* bk = (const float*)d_in[4];
  const float* Wv = (const float*)d_in[5];
  const float* bv = (const float*)d_in[6];
  const float* Wo = (const float*)d_in[7];
  const float* bo = (const float*)d_in[8];
  const float* relk = (const float*)d_in[9];
  const float* relv = (const float*)d_in[10];
  float* out = (float*)d_out;

  char* ws = (char*)d_ws;
  size_t off = 0;
  auto alloc = [&](size_t bytes) {
    char* p = ws + off;
    off += (bytes + 255) & ~(size_t)255;
    return p;
  };
  f16* xh = (f16*)alloc(8192ull * 1024 * 2);
  f16* Wqh = (f16*)alloc(1024ull * 1024 * 2);
  f16* Wkh = (f16*)alloc(1024ull * 1024 * 2);
  f16* Wvh = (f16*)alloc(1024ull * 1024 * 2);
  f16* Woh = (f16*)alloc(1024ull * 1024 * 2);
  f16* relKh = (f16*)alloc(2048ull * 64 * 2);
  f16* relVTh = (f16*)alloc(64ull * 2048 * 2);
  f16* Qh = (f16*)alloc(8192ull * 1024 * 2);
  f16* Kh = (f16*)alloc(8192ull * 1024 * 2);
  f16* Vth = (f16*)alloc(1024ull * 8192 * 2);
  f16* AOh = (f16*)alloc(8192ull * 1024 * 2);
  if (ws_size < off) return;  // workspace too small: fail loudly at validation

  pack_f16_kernel<<<32768, 256, 0, stream>>>(x, xh, 8192 * 1024);
  pack_f16_kernel<<<4096, 256, 0, stream>>>(Wq, Wqh, 1024 * 1024);
  pack_f16_kernel<<<4096, 256, 0, stream>>>(Wk, Wkh, 1024 * 1024);
  pack_f16_kernel<<<4096, 256, 0, stream>>>(Wv, Wvh, 1024 * 1024);
  pack_f16_kernel<<<4096, 256, 0, stream>>>(Wo, Woh, 1024 * 1024);
  pack_relk_kernel<<<512, 256, 0, stream>>>(relk, relKh);
  pack_relvt_kernel<<<512, 256, 0, stream>>>(relv, relVTh);

  dim3 g1(8, 64);  // N/128, M/128
  gemm_bt<0, 0><<<g1, 256, 0, stream>>>(xh, Wqh, bq, Qh, 8192, 1024, 1024, 1.0f);
  gemm_bt<0, 0><<<g1, 256, 0, stream>>>(xh, Wkh, bk, Kh, 8192, 1024, 1024, 0.125f);
  dim3 g2(64, 8);  // V^T = Wv @ x^T : M=1024, N=8192
  gemm_bt<0, 1><<<g2, 256, 0, stream>>>(Wvh, xh, bv, Vth, 1024, 8192, 1024, 1.0f);

  attn_kernel<<<2048, 256, 0, stream>>>(Qh, Kh, Vth, relKh, relVTh, AOh);

  gemm_bt<1, 0><<<g1, 256, 0, stream>>>(AOh, Woh, bo, out, 8192, 1024, 1024, 1.0f);
}